// Round 16
// baseline (811.726 us; speedup 1.0000x reference)
//
#include <hip/hip_runtime.h>
#include <hip/hip_bf16.h>

// Problem constants
#define TT   128
#define BB   256
#define MM   512
#define GG   2560
#define K1P  1024  // 940 padded to 1024 (4 waves x 8 chunks x 32)

typedef __attribute__((ext_vector_type(8))) short bf16x8;
typedef __attribute__((ext_vector_type(4))) short bf16x4;
typedef __attribute__((ext_vector_type(4))) float f32x4;

__device__ __forceinline__ float bf2f(unsigned short u){
  union { unsigned u; float f; } v; v.u = ((unsigned)u) << 16; return v.f;
}
__device__ __forceinline__ unsigned short f2bf(float f){
  union { float f; unsigned u; } v; v.f = f;
  unsigned r = v.u + 0x7fffu + ((v.u >> 16) & 1u);
  return (unsigned short)(r >> 16);
}
__device__ __forceinline__ float sigmoidf_(float x){ return 1.f/(1.f + __expf(-x)); }
__device__ __forceinline__ float tanhf_(float x){
  x = fminf(15.f, fmaxf(-15.f, x));
  float e = __expf(2.f*x);
  return (e - 1.f)/(e + 1.f);
}

// ---- MALL-coherent (sc0 sc1) helpers — the ONLY replay-safe cross-block
// exchange on this part. Session findings (do not revisit):
//   R8 : unscoped atomic + sc0 poll -> livelock
//   R10: sc0 flag separate from data -> race
//   R11: sc0 tagged-in-data         -> race
//   R12: sc0 data + MALL barrier    -> INTERMITTENT race (failed post-timing)
//   R15: raw s_barrier syncA + MFMA-between-arrive-and-poll -> core dump
// Conclusion: vmcnt-ack of an sc0 store != cross-CU visibility in XCD L2;
// keep all barriers as plain __syncthreads and all exchange at MALL scope.
__device__ __forceinline__ unsigned load_coh_u32(const unsigned* p){
  unsigned r;
  asm volatile("global_load_dword %0, %1, off sc0 sc1" : "=v"(r) : "v"(p) : "memory");
  asm volatile("s_waitcnt vmcnt(0)" ::: "memory");
  return r;
}
__device__ __forceinline__ bf16x8 load_h16(const void* p){
  bf16x8 r;
  asm volatile("global_load_dwordx4 %0, %1, off sc0 sc1" : "=v"(r) : "v"(p) : "memory");
  return r;
}
__device__ __forceinline__ void store_h32(void* p, unsigned v){
  asm volatile("global_store_dword %0, %1, off sc0 sc1" :: "v"(p), "v"(v) : "memory");
}
// plain cached 16B load as asm so OUR vmcnt bookkeeping stays exact
__device__ __forceinline__ bf16x8 ldg16(const void* p){
  bf16x8 r;
  asm volatile("global_load_dwordx4 %0, %1, off" : "=v"(r) : "v"(p) : "memory");
  return r;
}

// ---------------- staging kernels ----------------

__global__ __launch_bounds__(256) void stage_a(const float* __restrict__ word,
                                               const float* __restrict__ tag,
                                               const float* __restrict__ rel,
                                               const float* __restrict__ kin,
                                               unsigned short* __restrict__ A){
  long id = (long)blockIdx.x * 256 + threadIdx.x;     // chunk over 32768*128
  int row = (int)(id >> 7);
  int c8  = (int)(id & 127) * 8;
  bf16x8 o;
  #pragma unroll
  for (int j = 0; j < 8; ++j){
    int col = c8 + j; float v;
    if      (col < 300) v = word[(long)row*300 + col];
    else if (col < 364) v = tag [(long)row*64  + col-300];
    else if (col < 428) v = rel [(long)row*64  + col-364];
    else if (col < 940) v = kin [(long)row*512 + col-428];
    else v = 0.f;
    o[j] = (short)f2bf(v);
  }
  *reinterpret_cast<bf16x8*>(A + (long)row*K1P + c8) = o;
}

__global__ __launch_bounds__(256) void stage_wt(const float* __restrict__ Ww,
                                                const float* __restrict__ Wt,
                                                const float* __restrict__ Wr,
                                                const float* __restrict__ Wk,
                                                unsigned short* __restrict__ WT){
  long id = (long)blockIdx.x * 256 + threadIdx.x;   // 2560*1024
  int kk = (int)(id & 1023);
  int n  = (int)(id >> 10);
  float v;
  if      (kk < 300) v = Ww[(long)kk*GG + n];
  else if (kk < 364) v = Wt[(long)(kk-300)*GG + n];
  else if (kk < 428) v = Wr[(long)(kk-364)*GG + n];
  else if (kk < 940) v = Wk[(long)(kk-428)*GG + n];
  else v = 0.f;
  WT[(long)n*K1P + kk] = f2bf(v);
}

__global__ __launch_bounds__(256) void stage_wht(const float* __restrict__ Wh,
                                                 unsigned short* __restrict__ WhT){
  long id = (long)blockIdx.x * 256 + threadIdx.x;   // 2560*512
  int kk = (int)(id % MM);
  int n  = (int)(id / MM);
  WhT[(long)n*MM + kk] = f2bf(Wh[(long)kk*GG + n]);
}

__global__ __launch_bounds__(256) void init_h(const float* __restrict__ h0,
                                              unsigned short* __restrict__ hb){
  int id = blockIdx.x * 256 + threadIdx.x;          // 131072
  hb[id] = f2bf(h0[id]);
}

// ---------------- fused persistent recurrence + in-loop xp GEMM -------------
// R14-proven loop structure; three minimal edits:
//  (1) bt = blockIdx&7 (R9-verified co-location) so the group's shared A slab
//      is L2-served (read-only locality, no coherence dependence)
//  (2) A(t+1) issued just before syncB -> completed by its existing full
//      drain; next step starts with A in registers (no exposed A-wait)
//  (3) xp MFMAs at step top with no wait, overlapping the h-load MALL RT
// All barriers plain __syncthreads; exchange protocol byte-identical to
// R13/R14 (replay-validated).
__global__ __launch_bounds__(256, 1) void lstm_fused(const unsigned short* __restrict__ Abf,
                                                     const float* __restrict__ q,
                                                     const unsigned short* __restrict__ WT,
                                                     const unsigned short* __restrict__ WhT,
                                                     const float* __restrict__ bias,
                                                     const float* __restrict__ c0,
                                                     unsigned short* __restrict__ hb0,
                                                     unsigned short* __restrict__ hb1,
                                                     float* __restrict__ out,
                                                     unsigned* __restrict__ cnts){
  __shared__ float Part[4][5][2][16][20];        // [w][gate][rt][m][b pad20] 51.2 KB
  const int tid  = threadIdx.x;
  const int w    = tid >> 6, lane = tid & 63;
  const int lrow = lane & 15, lhi = lane >> 4;
  const int bt = blockIdx.x & 7, mc = blockIdx.x >> 3;
  const int b0 = bt * 32, m0 = mc * 16;
  unsigned* cnt = cnts + bt * 64;                // per-bt counter, own cacheline

  // ---- register-resident weights ----
  bf16x8 Wreg[5][8];                             // xp W, wave k-quarter (160 VGPR)
  #pragma unroll
  for (int g = 0; g < 5; ++g)
    #pragma unroll
    for (int c = 0; c < 8; ++c)
      Wreg[g][c] = *reinterpret_cast<const bf16x8*>(
          WT + (long)(g*MM + m0 + lrow)*K1P + w*256 + c*32 + lhi*8);
  bf16x8 Hreg[5][4];                             // Wh, wave k-quarter (80 VGPR)
  #pragma unroll
  for (int g = 0; g < 5; ++g)
    #pragma unroll
    for (int kf = 0; kf < 4; ++kf)
      Hreg[g][kf] = *reinterpret_cast<const bf16x8*>(
          WhT + (long)(g*MM + m0 + lrow)*MM + w*128 + kf*32 + lhi*8);

  // update-phase mapping: 2 states per thread
  const int bl = tid >> 3, mi2 = (tid & 7) * 2;
  const int rt2 = bl >> 4, brow = bl & 15;
  const int gb = b0 + bl, gm = m0 + mi2;
  float cx = c0[(long)gb*MM + gm];
  float cy = c0[(long)gb*MM + gm + 1];

  float bq[5][2];
  #pragma unroll
  for (int g = 0; g < 5; ++g){
    bq[g][0] = bias[g*MM + gm];
    bq[g][1] = bias[g*MM + gm + 1];
  }

  // per-lane A bases (t-running); q running offset
  const unsigned short* aB0 = Abf + (long)(b0 + 0*16 + lrow)*K1P + w*256 + lhi*8;
  const unsigned short* aB1 = Abf + (long)(b0 + 1*16 + lrow)*K1P + w*256 + lhi*8;
  const long ASTEP = (long)BB * K1P;
  const long qb0 = (long)gb*MM + gm;
  const long QSTEP = (long)BB*MM;
  float qx = q[qb0], qy = q[qb0 + 1];
  long qo = QSTEP;

  // ---- prologue: load A(0) and drain (loop then needs no A-wait at top) ----
  bf16x8 aw[2][8];
  #pragma unroll
  for (int c = 0; c < 8; ++c){
    aw[0][c] = ldg16(aB0 + c*32);
    aw[1][c] = ldg16(aB1 + c*32);
  }
  asm volatile("s_waitcnt vmcnt(0)" ::: "memory");
  __builtin_amdgcn_sched_barrier(0);

  for (int t = 0; t < TT; ++t){
    const unsigned short* hc = (t & 1) ? hb1 : hb0;
    unsigned short*       hn = (t & 1) ? hb0 : hb1;

    // issue h fragment loads (only VM ops outstanding), kf-major
    bf16x8 af[2][4];
    #pragma unroll
    for (int kf = 0; kf < 4; ++kf)
      #pragma unroll
      for (int rt = 0; rt < 2; ++rt)
        af[rt][kf] = load_h16(hc + (long)(b0 + rt*16 + lrow)*MM + w*128 + kf*32 + lhi*8);

    // xp MFMAs: A already in registers (drained last barrier) -> no wait;
    // these ~80 MFMAs run UNDER the h-load MALL latency
    f32x4 acc[5][2] = {};
    #pragma unroll
    for (int c = 0; c < 8; ++c)
      #pragma unroll
      for (int rt = 0; rt < 2; ++rt)
        #pragma unroll
        for (int g = 0; g < 5; ++g)
          acc[g][rt] = __builtin_amdgcn_mfma_f32_16x16x32_bf16(aw[rt][c], Wreg[g][c], acc[g][rt], 0, 0, 0);

    // h MFMAs with counted waits (only the 8 h loads are outstanding)
    #pragma unroll
    for (int kf = 0; kf < 4; ++kf){
      __builtin_amdgcn_sched_barrier(0);
      if      (kf == 0) asm volatile("s_waitcnt vmcnt(6)" ::: "memory");
      else if (kf == 1) asm volatile("s_waitcnt vmcnt(4)" ::: "memory");
      else if (kf == 2) asm volatile("s_waitcnt vmcnt(2)" ::: "memory");
      else              asm volatile("s_waitcnt vmcnt(0)" ::: "memory");
      __builtin_amdgcn_sched_barrier(0);
      #pragma unroll
      for (int rt = 0; rt < 2; ++rt)
        #pragma unroll
        for (int g = 0; g < 5; ++g)
          acc[g][rt] = __builtin_amdgcn_mfma_f32_16x16x32_bf16(af[rt][kf], Hreg[g][kf], acc[g][rt], 0, 0, 0);
    }

    // publish k-partials (D: col=m=lrow, row=b=lhi*4+j -> [m][b] contiguous x4)
    #pragma unroll
    for (int g = 0; g < 5; ++g)
      #pragma unroll
      for (int rt = 0; rt < 2; ++rt)
        *reinterpret_cast<f32x4*>(&Part[w][g][rt][lrow][lhi*4]) = acc[g][rt];
    __syncthreads();                               // syncA: Part ready

    // k-reduction + bias -> full gate preactivation
    float gv[5][2];
    #pragma unroll
    for (int g = 0; g < 5; ++g)
      #pragma unroll
      for (int x = 0; x < 2; ++x)
        gv[g][x] = Part[0][g][rt2][mi2+x][brow] + Part[1][g][rt2][mi2+x][brow]
                 + Part[2][g][rt2][mi2+x][brow] + Part[3][g][rt2][mi2+x][brow]
                 + bq[g][x];

    float hx, hy;
    {
      const float i_ = sigmoidf_(gv[0][0]);
      const float fd = sigmoidf_(gv[1][0]);
      const float fl = sigmoidf_(gv[2][0]);
      const float o_ = sigmoidf_(gv[3][0]);
      const float u_ = tanhf_(gv[4][0]);
      const float cn = i_*u_ + fd*qx + fl*cx;
      cx = cn; hx = o_*tanhf_(cn);
    }
    {
      const float i_ = sigmoidf_(gv[0][1]);
      const float fd = sigmoidf_(gv[1][1]);
      const float fl = sigmoidf_(gv[2][1]);
      const float o_ = sigmoidf_(gv[3][1]);
      const float u_ = tanhf_(gv[4][1]);
      const float cn = i_*u_ + fd*qy + fl*cy;
      cy = cn; hy = o_*tanhf_(cn);
    }

    const unsigned hv = (unsigned)f2bf(hx) | ((unsigned)f2bf(hy) << 16);
    if (t < TT - 1){
      store_h32(hn + (long)gb*MM + gm, hv);        // MALL store, drained at syncB

      // issue A(t+1) + q(t+1): completed by syncB's full drain (free)
      aB0 += ASTEP; aB1 += ASTEP;
      #pragma unroll
      for (int c = 0; c < 8; ++c){
        aw[0][c] = ldg16(aB0 + c*32);
        aw[1][c] = ldg16(aB1 + c*32);
      }
      qx = q[qo + qb0];
      qy = q[qo + qb0 + 1];
      qo += QSTEP;

      // per-bt barrier (R5/R13/R14-proven): syncB drains h store + A + q;
      // tid0 arrives + polls; syncC broadcasts.
      __syncthreads();                             // syncB
      if (tid == 0){
        __hip_atomic_fetch_add(cnt, 1u, __ATOMIC_RELAXED, __HIP_MEMORY_SCOPE_AGENT);
        const unsigned target = (unsigned)(t + 1) * 32u;
        unsigned spins = 0;
        while (load_coh_u32(cnt) < target){
          __builtin_amdgcn_s_sleep(1);
          if (++spins > (1u << 20)) break;         // safety valve
        }
      }
      __syncthreads();                             // syncC: release all waves
    } else {
      out[(long)gb*1024 + gm]           = hx;
      out[(long)gb*1024 + gm + 1]       = hy;
      out[(long)gb*1024 + 512 + gm]     = cx;
      out[(long)gb*1024 + 512 + gm + 1] = cy;
    }
  }
}

extern "C" void kernel_launch(void* const* d_in, const int* in_sizes, int n_in,
                              void* d_out, int out_size, void* d_ws, size_t ws_size,
                              hipStream_t stream){
  (void)in_sizes; (void)n_in; (void)out_size; (void)ws_size;
  const float* word = (const float*)d_in[0];
  const float* tag  = (const float*)d_in[1];
  const float* rel  = (const float*)d_in[2];
  const float* kin  = (const float*)d_in[3];
  const float* q    = (const float*)d_in[4];
  const float* h0   = (const float*)d_in[5];
  const float* c0   = (const float*)d_in[6];
  const float* Ww   = (const float*)d_in[7];
  const float* Wt   = (const float*)d_in[8];
  const float* Wr   = (const float*)d_in[9];
  const float* Wk   = (const float*)d_in[10];
  const float* Wh   = (const float*)d_in[11];
  const float* bias = (const float*)d_in[12];
  float* out = (float*)d_out;

  char* ws = (char*)d_ws;
  size_t off = 0;
  auto alloc = [&](size_t bytes)->void*{
    void* p = ws + off; off = (off + bytes + 255) & ~(size_t)255; return p;
  };
  unsigned short* Abf = (unsigned short*)alloc((size_t)TT*BB*K1P*2);   // 67.1 MB
  unsigned short* WT  = (unsigned short*)alloc((size_t)GG*K1P*2);      // 5.2 MB
  unsigned short* WhT = (unsigned short*)alloc((size_t)GG*MM*2);       // 2.6 MB
  unsigned short* hb0 = (unsigned short*)alloc((size_t)BB*MM*2);
  unsigned short* hb1 = (unsigned short*)alloc((size_t)BB*MM*2);
  unsigned*       cnt = (unsigned*)alloc(8 * 64 * sizeof(unsigned));   // per-bt counters

  hipMemsetAsync(cnt, 0, 8 * 64 * sizeof(unsigned), stream);

  stage_a  <<<dim3((int)(((long)TT*BB*(K1P/8) + 255)/256)), 256, 0, stream>>>(word, tag, rel, kin, Abf);
  stage_wt <<<dim3((int)(((long)GG*K1P + 255)/256)),        256, 0, stream>>>(Ww, Wt, Wr, Wk, WT);
  stage_wht<<<dim3((GG*MM + 255)/256),                      256, 0, stream>>>(Wh, WhT);
  init_h   <<<dim3((BB*MM + 255)/256),                      256, 0, stream>>>(h0, hb0);

  lstm_fused<<<dim3(256), 256, 0, stream>>>(Abf, q, WT, WhT, bias, c0, hb0, hb1, out, cnt);
}